// Round 14
// baseline (103.334 us; speedup 1.0000x reference)
//
#include <hip/hip_runtime.h>

#define LL   1024
#define LOG2E 1.44269504088896340736f
#define INV2PI 0.15915494309189535f
// LDS: Ks 64KB + Vs 64KB + xsd dbuf 20480B + cnt 64B
#define SMEM_BYTES (131072 + 20480 + 64)

typedef unsigned int       uint;
typedef unsigned short     ushort;
typedef unsigned long long ull;

typedef __attribute__((ext_vector_type(8)))  __bf16          bf16x8;
typedef __attribute__((ext_vector_type(8)))  unsigned short  u16x8;
typedef __attribute__((ext_vector_type(4)))  unsigned short  u16x4;
typedef __attribute__((ext_vector_type(2)))  uint            ui32x2;
typedef __attribute__((ext_vector_type(4)))  uint            ui32x4;
typedef __attribute__((ext_vector_type(4)))  float           f32x4;
typedef __attribute__((ext_vector_type(16))) float           f32x16;

static __device__ __forceinline__ ushort f2bf(float f){
  union {float f; uint u;} v; v.f = f;
  uint u = v.u + 0x7fffu + ((v.u >> 16) & 1u);  // RNE
  return (ushort)(u >> 16);
}
static __device__ __forceinline__ uint pack2(float a, float b){
  return (uint)f2bf(a) | ((uint)f2bf(b) << 16);
}
// truncating pack: one v_perm
static __device__ __forceinline__ uint packtrunc(float a, float b){
  union {float f; uint u;} x, y; x.f = a; y.f = b;
  return __builtin_amdgcn_perm(y.u, x.u, 0x07060302u);
}
static __device__ __forceinline__ bf16x8 ld_frag(const ushort* p){
  u16x8 t = *(const u16x8*)p;
  return __builtin_bit_cast(bf16x8, t);
}
static __device__ __forceinline__ bf16x8 cvt8(const float* p){
  float4 f0 = *(const float4*)p, f1 = *(const float4*)(p + 4);
  u16x8 t;
  t[0]=f2bf(f0.x); t[1]=f2bf(f0.y); t[2]=f2bf(f0.z); t[3]=f2bf(f0.w);
  t[4]=f2bf(f1.x); t[5]=f2bf(f1.y); t[6]=f2bf(f1.z); t[7]=f2bf(f1.w);
  return __builtin_bit_cast(bf16x8, t);
}

// C-layout -> B-frag half-exchange: a' = {a.lo, b.lo->hi}, b' = {a.hi->lo, b.hi}.
static __device__ __forceinline__ void plane32_swap(uint& a, uint& b){
  asm("v_permlane32_swap_b32 %0, %1" : "+v"(a), "+v"(b));
}

// One S^T/softmax/PV step for a 32-q tile against 64 keys held in frags.
// Single O accumulator (split-O spilled in R8 AND R11 — retired permanently).
static __device__ __forceinline__ void attn_tile(
    f32x16& O, float& rs, bf16x8 q0, bf16x8 q1,
    const bf16x8* kf, const bf16x8* vf)
{
  f32x16 zz = {};
  __builtin_amdgcn_s_setprio(1);
  f32x16 st0 = __builtin_amdgcn_mfma_f32_32x32x16_bf16(kf[0], q0, zz,  0,0,0);
  st0        = __builtin_amdgcn_mfma_f32_32x32x16_bf16(kf[1], q1, st0, 0,0,0);
  f32x16 st1 = __builtin_amdgcn_mfma_f32_32x32x16_bf16(kf[2], q0, zz,  0,0,0);
  st1        = __builtin_amdgcn_mfma_f32_32x32x16_bf16(kf[3], q1, st1, 0,0,0);
  __builtin_amdgcn_s_setprio(0);

  uint pr0[8], pr1[8];
  float s0 = 0.f, s1 = 0.f, s2 = 0.f, s3 = 0.f;   // short dep chains
  #pragma unroll
  for (int zi = 0; zi < 8; ++zi){
    float a0 = __builtin_amdgcn_exp2f(st0[2*zi]);
    float a1 = __builtin_amdgcn_exp2f(st0[2*zi+1]);
    float b0 = __builtin_amdgcn_exp2f(st1[2*zi]);
    float b1 = __builtin_amdgcn_exp2f(st1[2*zi+1]);
    s0 += a0; s1 += a1; s2 += b0; s3 += b1;
    pr0[zi] = packtrunc(a0, a1);
    pr1[zi] = packtrunc(b0, b1);
  }
  rs += (s0 + s1) + (s2 + s3);

  __builtin_amdgcn_s_setprio(1);
  #pragma unroll
  for (int c = 0; c < 4; ++c){
    const uint* pr = (c < 2) ? pr0 : pr1;
    const int g0 = 4*(c & 1);
    uint p0 = pr[g0+0], p1 = pr[g0+1], p2 = pr[g0+2], p3 = pr[g0+3];
    plane32_swap(p0, p2);
    plane32_swap(p1, p3);
    ui32x4 pb; pb[0]=p0; pb[1]=p1; pb[2]=p2; pb[3]=p3;
    O = __builtin_amdgcn_mfma_f32_32x32x16_bf16(
          vf[c], __builtin_bit_cast(bf16x8, pb), O, 0,0,0);
  }
  __builtin_amdgcn_s_setprio(0);
}

// ---------------------------------------------------------------------------
// Fused QKV-conv + flash attention (verified R4/R12 structure). Block = (bh,
// q-half of 512), 1024 threads = 16 waves. Phase 1 wave role-split: waves
// 8-15 stage x (dbuf) + conv V; waves 0-7 conv K (+PE,*log2e); every wave
// builds its own 32-q Q B-frags. Phase 2: barrier-free attention, ONE q-tile
// per wave, rolled kt loop, direct frag loads. R14: PE trig diet only —
// sin/cos via HW v_sin/v_cos on fract(rev) (freq pre-scaled by 1/2pi; arg in
// [0,1) so always in HW domain; ~4 instrs/angle vs ~14 OCML). pack2 stays
// the verified f2bf bit-twiddle (R13's hip_bf16 API pack didn't compile;
// R10's raw cvt_pk asm NaN'd).
//   Ks layout: [kt16][t2][cp2][hs2][key&31][j8]
//   Vs layout: [kt16][c4][hs2][d32][j8]
// ---------------------------------------------------------------------------
__global__ __launch_bounds__(1024, 1) void fused_kernel(
    const void* __restrict__ xr,
    const void* __restrict__ wqr,
    const void* __restrict__ wkr,
    const void* __restrict__ wvr,
    void* __restrict__ out)
{
  extern __shared__ __align__(16) char smem[];
  ushort* Ks = (ushort*)smem;                       // 32768 ushorts
  ushort* Vs = Ks + 32768;                          // 32768 ushorts
  uint (*xbuf)[20] = (uint (*)[20])(Vs + 32768);    // [2*128][20], 80B rows
  int* cnt = (int*)(smem + 131072 + 20480);

  const int bh   = blockIdx.x;
  const int qh   = blockIdx.y;          // 0..1: which 512 q rows
  const int tid  = threadIdx.x;
  const int wave = tid >> 6;
  const int lane = tid & 63;
  const int l16  = lane & 15;
  const int quad = lane >> 4;
  const int q32  = lane & 31;
  const int h    = lane >> 5;
  const int cw   = wave & 7;            // role-local wave index

  // dtype sniff (16 waves)
  bool is_bf;
  {
    uint w = ((const uint*)xr)[tid & 255];
    uint e = (w >> 7) & 0xFFu;
    ull b = __ballot((e >= 118u) && (e <= 132u));
    if (lane == 0) cnt[wave] = __popcll(b);
    __syncthreads();
    int s = 0;
    #pragma unroll
    for (int i = 0; i < 16; ++i) s += cnt[i];
    is_bf = s > 512;
  }

  // weight fragments (L1-hot): role-specific 16x16 frags; 32x32 Q A-frags all
  const void* wpr = (wave < 8) ? wkr : wvr;
  bf16x8 bwp[2], aq[2];
  #pragma unroll
  for (int nh = 0; nh < 2; ++nh){
    const int row = (bh & 7)*32 + nh*16 + l16;
    if (is_bf) bwp[nh] = ld_frag((const ushort*)wpr + (size_t)row*32 + quad*8);
    else       bwp[nh] = cvt8((const float*)wpr + (size_t)row*32 + quad*8);
  }
  {
    const int row = (bh & 7)*32 + q32;   // m = d = q32
    if (is_bf){
      aq[0] = ld_frag((const ushort*)wqr + (size_t)row*32 + h*8);
      aq[1] = ld_frag((const ushort*)wqr + (size_t)row*32 + 16 + h*8);
    } else {
      aq[0] = cvt8((const float*)wqr + (size_t)row*32 + h*8);
      aq[1] = cvt8((const float*)wqr + (size_t)row*32 + 16 + h*8);
    }
  }

  // per-lane PE frequencies in REVOLUTIONS (bh/quad only) — used by K-waves
  float fA[2], fB[2];
  #pragma unroll
  for (int nh = 0; nh < 2; ++nh){
    const int c0 = (bh & 7)*32 + nh*16 + quad*4;
    fA[nh] = INV2PI * __expf(-0.03597789207f * (float)c0);
    fB[nh] = INV2PI * __expf(-0.03597789207f * (float)(c0 + 2));
  }

  const int myoc = 4*qh + (wave >> 2);   // chunk holding this wave's q rows
  bf16x8 bq[2];                          // this wave's Q B-frags (k-halves)

  // staging thread mapping for waves 8-15: (c-pair 0..15, 4-l group 0..31)
  const int sid = tid & 511;
  const int cp = sid & 15, lg = sid >> 4;

  uint dw[4];
  if (wave >= 8){ // preload chunk 0
    const size_t rb = (size_t)(bh*32 + 2*cp)*LL + lg*4;
    if (is_bf){
      u16x4 e = *(const u16x4*)((const ushort*)xr + rb);
      u16x4 o = *(const u16x4*)((const ushort*)xr + rb + LL);
      #pragma unroll
      for (int j = 0; j < 4; ++j) dw[j] = (uint)e[j] | ((uint)o[j] << 16);
    } else {
      const float* xf = (const float*)xr;
      float4 e0 = *(const float4*)(xf + rb);
      float4 o0 = *(const float4*)(xf + rb + LL);
      dw[0]=pack2(e0.x,o0.x); dw[1]=pack2(e0.y,o0.y);
      dw[2]=pack2(e0.z,o0.z); dw[3]=pack2(e0.w,o0.w);
    }
  }

  // ---- Phase 1: conv over 8 chunks of 128 l ----
  for (int lc = 0; lc < 8; ++lc){
    uint (*xs)[20] = xbuf + (lc & 1)*128;
    if (wave >= 8){
      #pragma unroll
      for (int j = 0; j < 4; ++j) xs[lg*4 + j][cp] = dw[j];
    }
    __syncthreads();                     // xs visible; prev buffer free

    if (wave >= 8 && lc < 7){            // prefetch next chunk
      const size_t rb = (size_t)(bh*32 + 2*cp)*LL + (size_t)(lc+1)*128 + lg*4;
      if (is_bf){
        u16x4 e = *(const u16x4*)((const ushort*)xr + rb);
        u16x4 o = *(const u16x4*)((const ushort*)xr + rb + LL);
        #pragma unroll
        for (int j = 0; j < 4; ++j) dw[j] = (uint)e[j] | ((uint)o[j] << 16);
      } else {
        const float* xf = (const float*)xr;
        float4 e0 = *(const float4*)(xf + rb);
        float4 o0 = *(const float4*)(xf + rb + LL);
        dw[0]=pack2(e0.x,o0.x); dw[1]=pack2(e0.y,o0.y);
        dw[2]=pack2(e0.z,o0.z); dw[3]=pack2(e0.w,o0.w);
      }
    }

    // x A/B-frag: 16 l rows per role-wave, k = c = quad*8 + j
    bf16x8 ax = __builtin_bit_cast(bf16x8,
                  *(const ui32x4*)&xs[cw*16 + l16][quad*4]);
    const f32x4 z = {0.f,0.f,0.f,0.f};

    if (wave < 8){
      // K conv (swapped: D[m=d][n=l]) + PE (HW sin/cos on fract(rev)) + store
      f32x4 dk[2];
      #pragma unroll
      for (int nh = 0; nh < 2; ++nh)
        dk[nh] = __builtin_amdgcn_mfma_f32_16x16x32_bf16(bwp[nh], ax, z, 0,0,0);
      const int kl = lc*128 + cw*16 + l16;
      const int kbase = (kl >> 6)*2048 + ((kl >> 5) & 1)*1024
                      + (quad >> 1)*256 + (kl & 31)*8 + (quad & 1)*4;
      #pragma unroll
      for (int nh = 0; nh < 2; ++nh){
        const float ra  = __builtin_amdgcn_fractf(fA[nh] * (float)kl);
        const float rb2 = __builtin_amdgcn_fractf(fB[nh] * (float)kl);
        const float k0 = (dk[nh][0] + __builtin_amdgcn_sinf(ra))  * LOG2E;
        const float k1 = (dk[nh][1] + __builtin_amdgcn_cosf(ra))  * LOG2E;
        const float k2 = (dk[nh][2] + __builtin_amdgcn_sinf(rb2)) * LOG2E;
        const float k3 = (dk[nh][3] + __builtin_amdgcn_cosf(rb2)) * LOG2E;
        ui32x2 ww = { pack2(k0, k1), pack2(k2, k3) };
        *(ui32x2*)&Ks[kbase + nh*512] = ww;
      }
    } else {
      // V conv (normal: D[m=l][n=d]) + store
      f32x4 dv[2];
      #pragma unroll
      for (int nh = 0; nh < 2; ++nh)
        dv[nh] = __builtin_amdgcn_mfma_f32_16x16x32_bf16(ax, bwp[nh], z, 0,0,0);
      const int vl = lc*128 + cw*16 + quad*4;     // 4 consecutive keys
      const int vbase = (vl >> 6)*2048 + (cw & 3)*512
                      + (quad >> 1)*256 + (quad & 1)*4;
      #pragma unroll
      for (int nh = 0; nh < 2; ++nh){
        ui32x2 ww = { pack2(dv[nh][0], dv[nh][1]),
                      pack2(dv[nh][2], dv[nh][3]) };
        *(ui32x2*)&Vs[vbase + (nh*16 + l16)*8] = ww;
      }
    }

    // Q B-frags for this wave's own 32 q rows (wave-uniform branch)
    if (lc == myoc){
      const int xrow = (wave & 3)*32 + q32;
      bf16x8 bxl = __builtin_bit_cast(bf16x8, *(const ui32x4*)&xs[xrow][h*4]);
      bf16x8 bxh = __builtin_bit_cast(bf16x8, *(const ui32x4*)&xs[xrow][8 + h*4]);
      f32x16 zz = {};
      f32x16 dq = __builtin_amdgcn_mfma_f32_32x32x16_bf16(aq[0], bxl, zz, 0,0,0);
      dq        = __builtin_amdgcn_mfma_f32_32x32x16_bf16(aq[1], bxh, dq, 0,0,0);
      uint prq[8];
      #pragma unroll
      for (int zi = 0; zi < 8; ++zi) prq[zi] = pack2(dq[2*zi], dq[2*zi+1]);
      #pragma unroll
      for (int hf = 0; hf < 2; ++hf){
        const int g0 = 4*hf;
        uint p0 = prq[g0+0], p1 = prq[g0+1], p2 = prq[g0+2], p3 = prq[g0+3];
        plane32_swap(p0, p2);
        plane32_swap(p1, p3);
        ui32x4 pb; pb[0]=p0; pb[1]=p1; pb[2]=p2; pb[3]=p3;
        bq[hf] = __builtin_bit_cast(bf16x8, pb);
      }
    }
  }
  __syncthreads();   // Ks/Vs complete; LDS is read-only from here on

  // ---- Phase 2: attention (no barriers), direct frag loads per kt ----
  const ushort* kb = Ks + h*256 + q32*8;
  const ushort* vb = Vs + h*256 + q32*8;

  f32x16 O = {};
  float rs = 0.f;

  #pragma unroll 1
  for (int kt = 0; kt < 16; ++kt){
    bf16x8 kf[4], vf[4];
    #pragma unroll
    for (int i = 0; i < 4; ++i){
      kf[i] = ld_frag(kb + kt*2048 + i*512);
      vf[i] = ld_frag(vb + kt*2048 + i*512);
    }
    attn_tile(O, rs, bq[0], bq[1], kf, vf);
  }

  // lane holds keys with bit2==h; partner holds the rest
  rs += __shfl_xor(rs, 32);
  const float inv = 1.f / rs;

  // epilogue: D[m=d][n=q]: d = (reg&3)+8(reg>>2)+4h, q = lane&31 (coalesced)
  const int qg0 = qh*512 + wave*32 + q32;
  #pragma unroll
  for (int reg = 0; reg < 16; ++reg){
    const int d = (reg & 3) + 8*(reg >> 2) + 4*h;
    const float v = O[reg] * inv;
    const size_t off = ((size_t)(bh*32 + d))*LL + qg0;
    if (is_bf) ((ushort*)out)[off] = f2bf(v);
    else       ((float*)out)[off]  = v;
  }
}

extern "C" void kernel_launch(void* const* d_in, const int* in_sizes, int n_in,
                              void* d_out, int out_size, void* d_ws, size_t ws_size,
                              hipStream_t stream) {
  (void)d_ws; (void)ws_size; (void)in_sizes; (void)n_in; (void)out_size;
  static bool inited = false;
  if (!inited){
    (void)hipFuncSetAttribute(reinterpret_cast<const void*>(fused_kernel),
                              hipFuncAttributeMaxDynamicSharedMemorySize,
                              SMEM_BYTES);
    inited = true;
  }
  fused_kernel<<<dim3(128, 2), 1024, SMEM_BYTES, stream>>>(
      d_in[0], d_in[1], d_in[2], d_in[3], d_out);
}

// Round 15
// 101.213 us; speedup vs baseline: 1.0210x; 1.0210x over previous
//
#include <hip/hip_runtime.h>

#define LL   1024
#define LOG2E 1.44269504088896340736f
#define INV2PI 0.15915494309189535f
// LDS: Ks 64KB + Vs 64KB + xsd dbuf 20480B + cnt 64B
#define SMEM_BYTES (131072 + 20480 + 64)

typedef unsigned int       uint;
typedef unsigned short     ushort;
typedef unsigned long long ull;

typedef __attribute__((ext_vector_type(8)))  __bf16          bf16x8;
typedef __attribute__((ext_vector_type(8)))  unsigned short  u16x8;
typedef __attribute__((ext_vector_type(4)))  unsigned short  u16x4;
typedef __attribute__((ext_vector_type(2)))  uint            ui32x2;
typedef __attribute__((ext_vector_type(4)))  uint            ui32x4;
typedef __attribute__((ext_vector_type(4)))  float           f32x4;
typedef __attribute__((ext_vector_type(16))) float           f32x16;

static __device__ __forceinline__ ushort f2bf(float f){
  union {float f; uint u;} v; v.f = f;
  uint u = v.u + 0x7fffu + ((v.u >> 16) & 1u);  // RNE
  return (ushort)(u >> 16);
}
static __device__ __forceinline__ uint pack2(float a, float b){
  return (uint)f2bf(a) | ((uint)f2bf(b) << 16);
}
// truncating pack: one v_perm
static __device__ __forceinline__ uint packtrunc(float a, float b){
  union {float f; uint u;} x, y; x.f = a; y.f = b;
  return __builtin_amdgcn_perm(y.u, x.u, 0x07060302u);
}
static __device__ __forceinline__ bf16x8 ld_frag(const ushort* p){
  u16x8 t = *(const u16x8*)p;
  return __builtin_bit_cast(bf16x8, t);
}
static __device__ __forceinline__ bf16x8 cvt8(const float* p){
  float4 f0 = *(const float4*)p, f1 = *(const float4*)(p + 4);
  u16x8 t;
  t[0]=f2bf(f0.x); t[1]=f2bf(f0.y); t[2]=f2bf(f0.z); t[3]=f2bf(f0.w);
  t[4]=f2bf(f1.x); t[5]=f2bf(f1.y); t[6]=f2bf(f1.z); t[7]=f2bf(f1.w);
  return __builtin_bit_cast(bf16x8, t);
}

// C-layout -> B-frag half-exchange: a' = {a.lo, b.lo->hi}, b' = {a.hi->lo, b.hi}.
static __device__ __forceinline__ void plane32_swap(uint& a, uint& b){
  asm("v_permlane32_swap_b32 %0, %1" : "+v"(a), "+v"(b));
}

// One S^T/softmax/PV step for a 32-q tile against 64 keys held in frags.
// Single O accumulator (split-O spilled in R8 AND R11 — retired permanently).
static __device__ __forceinline__ void attn_tile(
    f32x16& O, float& rs, bf16x8 q0, bf16x8 q1,
    const bf16x8* kf, const bf16x8* vf)
{
  f32x16 zz = {};
  __builtin_amdgcn_s_setprio(1);
  f32x16 st0 = __builtin_amdgcn_mfma_f32_32x32x16_bf16(kf[0], q0, zz,  0,0,0);
  st0        = __builtin_amdgcn_mfma_f32_32x32x16_bf16(kf[1], q1, st0, 0,0,0);
  f32x16 st1 = __builtin_amdgcn_mfma_f32_32x32x16_bf16(kf[2], q0, zz,  0,0,0);
  st1        = __builtin_amdgcn_mfma_f32_32x32x16_bf16(kf[3], q1, st1, 0,0,0);
  __builtin_amdgcn_s_setprio(0);

  uint pr0[8], pr1[8];
  float s0 = 0.f, s1 = 0.f, s2 = 0.f, s3 = 0.f;   // short dep chains
  #pragma unroll
  for (int zi = 0; zi < 8; ++zi){
    float a0 = __builtin_amdgcn_exp2f(st0[2*zi]);
    float a1 = __builtin_amdgcn_exp2f(st0[2*zi+1]);
    float b0 = __builtin_amdgcn_exp2f(st1[2*zi]);
    float b1 = __builtin_amdgcn_exp2f(st1[2*zi+1]);
    s0 += a0; s1 += a1; s2 += b0; s3 += b1;
    pr0[zi] = packtrunc(a0, a1);
    pr1[zi] = packtrunc(b0, b1);
  }
  rs += (s0 + s1) + (s2 + s3);

  __builtin_amdgcn_s_setprio(1);
  #pragma unroll
  for (int c = 0; c < 4; ++c){
    const uint* pr = (c < 2) ? pr0 : pr1;
    const int g0 = 4*(c & 1);
    uint p0 = pr[g0+0], p1 = pr[g0+1], p2 = pr[g0+2], p3 = pr[g0+3];
    plane32_swap(p0, p2);
    plane32_swap(p1, p3);
    ui32x4 pb; pb[0]=p0; pb[1]=p1; pb[2]=p2; pb[3]=p3;
    O = __builtin_amdgcn_mfma_f32_32x32x16_bf16(
          vf[c], __builtin_bit_cast(bf16x8, pb), O, 0,0,0);
  }
  __builtin_amdgcn_s_setprio(0);
}

// ---------------------------------------------------------------------------
// Fused QKV-conv + flash attention (verified R4/R12/R14 structure). Block =
// (bh, q-half of 512), 1024 threads = 16 waves. Phase 1 wave role-split:
// waves 8-15 stage x + conv V; waves 0-7 conv K (+PE via HW sin/cos on
// fract(rev)); every wave builds its own 32-q Q B-frags. R15: FULL x
// preload — all 8 chunks' global loads issued in the preamble (loads retire
// in issue order, so each chunk's vmcnt wait is covered by preceding chunks'
// work; the 1-deep prefetch left chunk c+1's cold-HBM latency exposed when
// a chunk's wall time was shorter than the load latency). lc loop unrolled
// so dw[lc] is statically indexed (rule #20). Phase 2: barrier-free
// attention, ONE q-tile per wave, rolled kt loop, direct frag loads.
//   Ks layout: [kt16][t2][cp2][hs2][key&31][j8]
//   Vs layout: [kt16][c4][hs2][d32][j8]
// ---------------------------------------------------------------------------
__global__ __launch_bounds__(1024, 1) void fused_kernel(
    const void* __restrict__ xr,
    const void* __restrict__ wqr,
    const void* __restrict__ wkr,
    const void* __restrict__ wvr,
    void* __restrict__ out)
{
  extern __shared__ __align__(16) char smem[];
  ushort* Ks = (ushort*)smem;                       // 32768 ushorts
  ushort* Vs = Ks + 32768;                          // 32768 ushorts
  uint (*xbuf)[20] = (uint (*)[20])(Vs + 32768);    // [2*128][20], 80B rows
  int* cnt = (int*)(smem + 131072 + 20480);

  const int bh   = blockIdx.x;
  const int qh   = blockIdx.y;          // 0..1: which 512 q rows
  const int tid  = threadIdx.x;
  const int wave = tid >> 6;
  const int lane = tid & 63;
  const int l16  = lane & 15;
  const int quad = lane >> 4;
  const int q32  = lane & 31;
  const int h    = lane >> 5;
  const int cw   = wave & 7;            // role-local wave index

  // dtype sniff (16 waves)
  bool is_bf;
  {
    uint w = ((const uint*)xr)[tid & 255];
    uint e = (w >> 7) & 0xFFu;
    ull b = __ballot((e >= 118u) && (e <= 132u));
    if (lane == 0) cnt[wave] = __popcll(b);
    __syncthreads();
    int s = 0;
    #pragma unroll
    for (int i = 0; i < 16; ++i) s += cnt[i];
    is_bf = s > 512;
  }

  // weight fragments (L1-hot): role-specific 16x16 frags; 32x32 Q A-frags all
  const void* wpr = (wave < 8) ? wkr : wvr;
  bf16x8 bwp[2], aq[2];
  #pragma unroll
  for (int nh = 0; nh < 2; ++nh){
    const int row = (bh & 7)*32 + nh*16 + l16;
    if (is_bf) bwp[nh] = ld_frag((const ushort*)wpr + (size_t)row*32 + quad*8);
    else       bwp[nh] = cvt8((const float*)wpr + (size_t)row*32 + quad*8);
  }
  {
    const int row = (bh & 7)*32 + q32;   // m = d = q32
    if (is_bf){
      aq[0] = ld_frag((const ushort*)wqr + (size_t)row*32 + h*8);
      aq[1] = ld_frag((const ushort*)wqr + (size_t)row*32 + 16 + h*8);
    } else {
      aq[0] = cvt8((const float*)wqr + (size_t)row*32 + h*8);
      aq[1] = cvt8((const float*)wqr + (size_t)row*32 + 16 + h*8);
    }
  }

  // per-lane PE frequencies in REVOLUTIONS (bh/quad only) — used by K-waves
  float fA[2], fB[2];
  #pragma unroll
  for (int nh = 0; nh < 2; ++nh){
    const int c0 = (bh & 7)*32 + nh*16 + quad*4;
    fA[nh] = INV2PI * __expf(-0.03597789207f * (float)c0);
    fB[nh] = INV2PI * __expf(-0.03597789207f * (float)(c0 + 2));
  }

  const int myoc = 4*qh + (wave >> 2);   // chunk holding this wave's q rows
  bf16x8 bq[2];                          // this wave's Q B-frags (k-halves)

  // staging thread mapping for waves 8-15: (c-pair 0..15, 4-l group 0..31)
  const int sid = tid & 511;
  const int cp = sid & 15, lg = sid >> 4;

  // ---- full x preload: issue ALL 8 chunks' loads now (staging waves) ----
  uint dw[8][4];
  if (wave >= 8){
    if (is_bf){
      #pragma unroll
      for (int c = 0; c < 8; ++c){
        const size_t rb = (size_t)(bh*32 + 2*cp)*LL + (size_t)c*128 + lg*4;
        u16x4 e = *(const u16x4*)((const ushort*)xr + rb);
        u16x4 o = *(const u16x4*)((const ushort*)xr + rb + LL);
        #pragma unroll
        for (int j = 0; j < 4; ++j) dw[c][j] = (uint)e[j] | ((uint)o[j] << 16);
      }
    } else {
      #pragma unroll
      for (int c = 0; c < 8; ++c){
        const size_t rb = (size_t)(bh*32 + 2*cp)*LL + (size_t)c*128 + lg*4;
        const float* xf = (const float*)xr;
        float4 e0 = *(const float4*)(xf + rb);
        float4 o0 = *(const float4*)(xf + rb + LL);
        dw[c][0]=pack2(e0.x,o0.x); dw[c][1]=pack2(e0.y,o0.y);
        dw[c][2]=pack2(e0.z,o0.z); dw[c][3]=pack2(e0.w,o0.w);
      }
    }
  }

  // ---- Phase 1: conv over 8 chunks of 128 l (unrolled: dw[lc] static) ----
  #pragma unroll
  for (int lc = 0; lc < 8; ++lc){
    uint (*xs)[20] = xbuf + (lc & 1)*128;
    if (wave >= 8){
      #pragma unroll
      for (int j = 0; j < 4; ++j) xs[lg*4 + j][cp] = dw[lc][j];
    }
    __syncthreads();                     // xs visible; prev buffer free

    // x A/B-frag: 16 l rows per role-wave, k = c = quad*8 + j
    bf16x8 ax = __builtin_bit_cast(bf16x8,
                  *(const ui32x4*)&xs[cw*16 + l16][quad*4]);
    const f32x4 z = {0.f,0.f,0.f,0.f};

    if (wave < 8){
      // K conv (swapped: D[m=d][n=l]) + PE (HW sin/cos on fract(rev)) + store
      f32x4 dk[2];
      #pragma unroll
      for (int nh = 0; nh < 2; ++nh)
        dk[nh] = __builtin_amdgcn_mfma_f32_16x16x32_bf16(bwp[nh], ax, z, 0,0,0);
      const int kl = lc*128 + cw*16 + l16;
      const int kbase = (kl >> 6)*2048 + ((kl >> 5) & 1)*1024
                      + (quad >> 1)*256 + (kl & 31)*8 + (quad & 1)*4;
      #pragma unroll
      for (int nh = 0; nh < 2; ++nh){
        const float ra  = __builtin_amdgcn_fractf(fA[nh] * (float)kl);
        const float rb2 = __builtin_amdgcn_fractf(fB[nh] * (float)kl);
        const float k0 = (dk[nh][0] + __builtin_amdgcn_sinf(ra))  * LOG2E;
        const float k1 = (dk[nh][1] + __builtin_amdgcn_cosf(ra))  * LOG2E;
        const float k2 = (dk[nh][2] + __builtin_amdgcn_sinf(rb2)) * LOG2E;
        const float k3 = (dk[nh][3] + __builtin_amdgcn_cosf(rb2)) * LOG2E;
        ui32x2 ww = { pack2(k0, k1), pack2(k2, k3) };
        *(ui32x2*)&Ks[kbase + nh*512] = ww;
      }
    } else {
      // V conv (normal: D[m=l][n=d]) + store
      f32x4 dv[2];
      #pragma unroll
      for (int nh = 0; nh < 2; ++nh)
        dv[nh] = __builtin_amdgcn_mfma_f32_16x16x32_bf16(ax, bwp[nh], z, 0,0,0);
      const int vl = lc*128 + cw*16 + quad*4;     // 4 consecutive keys
      const int vbase = (vl >> 6)*2048 + (cw & 3)*512
                      + (quad >> 1)*256 + (quad & 1)*4;
      #pragma unroll
      for (int nh = 0; nh < 2; ++nh){
        ui32x2 ww = { pack2(dv[nh][0], dv[nh][1]),
                      pack2(dv[nh][2], dv[nh][3]) };
        *(ui32x2*)&Vs[vbase + (nh*16 + l16)*8] = ww;
      }
    }

    // Q B-frags for this wave's own 32 q rows (wave-uniform branch)
    if (lc == myoc){
      const int xrow = (wave & 3)*32 + q32;
      bf16x8 bxl = __builtin_bit_cast(bf16x8, *(const ui32x4*)&xs[xrow][h*4]);
      bf16x8 bxh = __builtin_bit_cast(bf16x8, *(const ui32x4*)&xs[xrow][8 + h*4]);
      f32x16 zz = {};
      f32x16 dq = __builtin_amdgcn_mfma_f32_32x32x16_bf16(aq[0], bxl, zz, 0,0,0);
      dq        = __builtin_amdgcn_mfma_f32_32x32x16_bf16(aq[1], bxh, dq, 0,0,0);
      uint prq[8];
      #pragma unroll
      for (int zi = 0; zi < 8; ++zi) prq[zi] = pack2(dq[2*zi], dq[2*zi+1]);
      #pragma unroll
      for (int hf = 0; hf < 2; ++hf){
        const int g0 = 4*hf;
        uint p0 = prq[g0+0], p1 = prq[g0+1], p2 = prq[g0+2], p3 = prq[g0+3];
        plane32_swap(p0, p2);
        plane32_swap(p1, p3);
        ui32x4 pb; pb[0]=p0; pb[1]=p1; pb[2]=p2; pb[3]=p3;
        bq[hf] = __builtin_bit_cast(bf16x8, pb);
      }
    }
  }
  __syncthreads();   // Ks/Vs complete; LDS is read-only from here on

  // ---- Phase 2: attention (no barriers), direct frag loads per kt ----
  const ushort* kb = Ks + h*256 + q32*8;
  const ushort* vb = Vs + h*256 + q32*8;

  f32x16 O = {};
  float rs = 0.f;

  #pragma unroll 1
  for (int kt = 0; kt < 16; ++kt){
    bf16x8 kf[4], vf[4];
    #pragma unroll
    for (int i = 0; i < 4; ++i){
      kf[i] = ld_frag(kb + kt*2048 + i*512);
      vf[i] = ld_frag(vb + kt*2048 + i*512);
    }
    attn_tile(O, rs, bq[0], bq[1], kf, vf);
  }

  // lane holds keys with bit2==h; partner holds the rest
  rs += __shfl_xor(rs, 32);
  const float inv = 1.f / rs;

  // epilogue: D[m=d][n=q]: d = (reg&3)+8(reg>>2)+4h, q = lane&31 (coalesced)
  const int qg0 = qh*512 + wave*32 + q32;
  #pragma unroll
  for (int reg = 0; reg < 16; ++reg){
    const int d = (reg & 3) + 8*(reg >> 2) + 4*h;
    const float v = O[reg] * inv;
    const size_t off = ((size_t)(bh*32 + d))*LL + qg0;
    if (is_bf) ((ushort*)out)[off] = f2bf(v);
    else       ((float*)out)[off]  = v;
  }
}

extern "C" void kernel_launch(void* const* d_in, const int* in_sizes, int n_in,
                              void* d_out, int out_size, void* d_ws, size_t ws_size,
                              hipStream_t stream) {
  (void)d_ws; (void)ws_size; (void)in_sizes; (void)n_in; (void)out_size;
  static bool inited = false;
  if (!inited){
    (void)hipFuncSetAttribute(reinterpret_cast<const void*>(fused_kernel),
                              hipFuncAttributeMaxDynamicSharedMemorySize,
                              SMEM_BYTES);
    inited = true;
  }
  fused_kernel<<<dim3(128, 2), 1024, SMEM_BYTES, stream>>>(
      d_in[0], d_in[1], d_in[2], d_in[3], d_out);
}